// Round 1
// baseline (602.925 us; speedup 1.0000x reference)
//
#include <hip/hip_runtime.h>
#include <hip/hip_cooperative_groups.h>

namespace cg = cooperative_groups;

typedef unsigned short u16;
typedef unsigned int u32;
typedef __attribute__((ext_vector_type(8))) short bf16x8;
typedef __attribute__((ext_vector_type(4))) float f32x4;

#define B_    128
#define P_    2048
#define NC_   10
#define F_    160      // NC*CLO
#define NTHR  512

// cooperative (primary) path
#define CBLK  256      // persistent blocks: 1 per CU
#define CPPB  8        // p-tiles per block (held in LDS across all 3 iterations)

// fallback path (previous 6-kernel structure)
#define GBLK  512
#define XS    40
#define WS    40

__device__ __forceinline__ u16 f2bf(float f) {
    union { float f; unsigned u; } v; v.f = f;
    unsigned r = v.u + 0x7FFFu + ((v.u >> 16) & 1u);   // RNE
    return (u16)(r >> 16);
}
__device__ __forceinline__ float bf2f(u16 h) {
    union { unsigned u; float f; } v; v.u = ((unsigned)h) << 16;
    return v.f;
}

// squash along NP=32, cast bf16, write xb[p][b][chunk] with chunk XOR-swizzle
// (slot' = slot ^ ((b>>1)&3)) so the consumer's unpadded LDS image is
// bank-conflict-free on ds_read_b128. 4 lanes per (b,p) pair.
__global__ void k_squash_x(const float* __restrict__ t, u16* __restrict__ xb) {
    int g = blockIdx.x * 256 + threadIdx.x;
    int pair = g >> 2, sub = g & 3;
    int p = pair & 2047, b = pair >> 11;
    const float4* tg = (const float4*)t;
    int fi = pair * 8 + sub * 2;
    float4 va = tg[fi], vb = tg[fi + 1];
    float ss = va.x*va.x + va.y*va.y + va.z*va.z + va.w*va.w
             + vb.x*vb.x + vb.y*vb.y + vb.z*vb.z + vb.w*vb.w;
    ss += __shfl_xor(ss, 1);      // quad holds the full 32-elem sum
    ss += __shfl_xor(ss, 2);
    float fct = ss / ((1.f + ss) * sqrtf(ss));
    u16 h[8] __attribute__((aligned(16)));
    h[0]=f2bf(va.x*fct); h[1]=f2bf(va.y*fct); h[2]=f2bf(va.z*fct); h[3]=f2bf(va.w*fct);
    h[4]=f2bf(vb.x*fct); h[5]=f2bf(vb.y*fct); h[6]=f2bf(vb.z*fct); h[7]=f2bf(vb.w*fct);
    int sw = sub ^ ((b >> 1) & 3);
    *(uint4*)(xb + (p * 128 + b) * 32 + sw * 8) = *(const uint4*)h;
}

// weight[p][k][f] fp32 -> wb[p][f][k] bf16 (transpose via LDS), same chunk swizzle
__global__ void k_wt(const float* __restrict__ w, u16* __restrict__ wb) {
    __shared__ u16 wl[32 * F_];
    int p = blockIdx.x, tid = threadIdx.x;
    const float4* wp = (const float4*)(w + p * 32 * F_);
    for (int e4 = tid; e4 < 1280; e4 += 256) {
        float4 v = wp[e4];
        u16 h[4] __attribute__((aligned(8)));
        h[0]=f2bf(v.x); h[1]=f2bf(v.y); h[2]=f2bf(v.z); h[3]=f2bf(v.w);
        *(ushort4*)(wl + e4 * 4) = *(const ushort4*)h;
    }
    __syncthreads();
    u16* wo = wb + p * F_ * 32;
    for (int sid = tid; sid < 640; sid += 256) {
        int f = sid >> 2, k0 = (sid & 3) << 3;
        u16 tmp[8] __attribute__((aligned(16)));
#pragma unroll
        for (int j = 0; j < 8; ++j) tmp[j] = wl[(k0 + j) * F_ + f];
        int sw = (sid & 3) ^ ((f >> 1) & 3);
        *(uint4*)(wo + f * 32 + sw * 8) = *(const uint4*)tmp;
    }
}

// ---------------- persistent cooperative kernel: all 3 routing iterations ----
// 256 blocks x 512 threads, 1 block/CU. Each block stages its 8 p-tiles of x,w
// into LDS ONCE (147,456 B, unpadded + XOR-swizzled) and keeps them for all 3
// iterations. 2 waves/SIMD -> 256-VGPR budget: u[10] fragments live in regs so
// the MFMA is computed once per (p, iteration) instead of twice.
__global__ __launch_bounds__(NTHR, 2) void k_route(
        const u16* __restrict__ xb, const u16* __restrict__ wb,
        u16* __restrict__ s_part, float* __restrict__ v0,
        float* __restrict__ vs, float* __restrict__ out)
{
    __shared__ u16 xt[CPPB * 128 * 32];    // 65,536 B
    __shared__ u16 wt[CPPB * 160 * 32];    // 81,920 B
    __shared__ float red[2 * NTHR];        //  4,096 B  (reduction scratch)

    const int tid = threadIdx.x, blk = blockIdx.x;
    const int L = tid & 63, wv = tid >> 6;
    const int q = L >> 4, col = L & 15;
    const int b = wv * 16 + col;
    const int qs = (q ^ ((col >> 1) & 3)) * 8;   // swizzled k-slot (short offset)
    const int p0 = blk * CPPB;

    // ---- stage all 8 p-tiles (one-time HBM read; BW-bound ~6 us grid-wide)
    {
        const uint4* xg = (const uint4*)(xb + (size_t)p0 * 4096);
        const uint4* wg = (const uint4*)(wb + (size_t)p0 * 5120);
        uint4 rx[8], rw[10];
#pragma unroll
        for (int i = 0; i < 8; ++i)  rx[i] = xg[i * NTHR + tid];
#pragma unroll
        for (int i = 0; i < 10; ++i) rw[i] = wg[i * NTHR + tid];
        uint4* xl = (uint4*)xt; uint4* wl4 = (uint4*)wt;
#pragma unroll
        for (int i = 0; i < 8; ++i)  xl[i * NTHR + tid] = rx[i];
#pragma unroll
        for (int i = 0; i < 10; ++i) wl4[i * NTHR + tid] = rw[i];
    }
    __syncthreads();

    cg::grid_group grid = cg::this_grid();

    for (int itn = 0; itn < 3; ++itn) {
        f32x4 s_acc[NC_];
#pragma unroll
        for (int n = 0; n < NC_; ++n) s_acc[n] = (f32x4){0.f, 0.f, 0.f, 0.f};

        if (itn == 0) {
            // c = 0.1 uniform: pure chained MFMA over the 8 resident p's
            for (int pp = 0; pp < CPPB; ++pp) {
                bf16x8 bfrag = *(const bf16x8*)&xt[(pp * 128 + b) * 32 + qs];
#pragma unroll
                for (int n = 0; n < NC_; ++n) {
                    bf16x8 afrag = *(const bf16x8*)&wt[(pp * 160 + n * 16 + col) * 32 + qs];
                    s_acc[n] = __builtin_amdgcn_mfma_f32_16x16x32_bf16(afrag, bfrag, s_acc[n], 0, 0, 0);
                }
            }
        } else {
            const float* vp = (itn == 1) ? v0 : vs;   // logits use v0, then v0+v1
            float4 vv[NC_];
#pragma unroll
            for (int n = 0; n < NC_; ++n)
                vv[n] = *(const float4*)(vp + b * F_ + n * 16 + q * 4);
            for (int pp = 0; pp < CPPB; ++pp) {
                bf16x8 bfrag = *(const bf16x8*)&xt[(pp * 128 + b) * 32 + qs];
                f32x4 u[NC_];
                float tt[NC_];
#pragma unroll
                for (int n = 0; n < NC_; ++n) {      // u computed ONCE, kept in regs
                    bf16x8 afrag = *(const bf16x8*)&wt[(pp * 160 + n * 16 + col) * 32 + qs];
                    f32x4 z = (f32x4){0.f, 0.f, 0.f, 0.f};
                    u[n] = __builtin_amdgcn_mfma_f32_16x16x32_bf16(afrag, bfrag, z, 0, 0, 0);
                }
#pragma unroll
                for (int n = 0; n < NC_; ++n) {
                    float t = u[n][0]*vv[n].x + u[n][1]*vv[n].y + u[n][2]*vv[n].z + u[n][3]*vv[n].w;
                    t += __shfl_xor(t, 16);          // full 16-elem dot over k'
                    t += __shfl_xor(t, 32);
                    tt[n] = t;
                }
                float mx = tt[0];
#pragma unroll
                for (int n = 1; n < NC_; ++n) mx = fmaxf(mx, tt[n]);
                float den = 0.f;
#pragma unroll
                for (int n = 0; n < NC_; ++n) { tt[n] = __expf(tt[n] - mx); den += tt[n]; }
                float inv = 1.f / den;
#pragma unroll
                for (int n = 0; n < NC_; ++n) {
                    float cf = tt[n] * inv;
#pragma unroll
                    for (int r = 0; r < 4; ++r) s_acc[n][r] += cf * u[n][r];
                }
            }
        }

        // write this block's bf16 partials (256 groups -> 10.5 MB per pass)
        {
            u16* sp = s_part + blk * (B_ * F_);
            const float sc = (itn == 0) ? 0.1f : 1.f;
#pragma unroll
            for (int n = 0; n < NC_; ++n) {
                u16 h[4] __attribute__((aligned(8)));
#pragma unroll
                for (int r = 0; r < 4; ++r) h[r] = f2bf(s_acc[n][r] * sc);
                *(ushort4*)(sp + b * F_ + n * 16 + q * 4) = *(const ushort4*)h;
            }
        }
        __threadfence();
        grid.sync();

        // ---- reduction: 320 jobs x 32 output-pairs; threads 0-255 job=blk,
        //      threads 256-511 job=blk+256 (valid for blk<64)
        {
            const int jtid = tid & 255;
            const int jblk = (tid < 256) ? blk : blk + CBLK;
            const bool valid = (jblk < 320);
            const int pid = jtid & 31, part = jtid >> 5;
            float a0 = 0.f, a1 = 0.f;
            if (valid) {
                const u32* spp = (const u32*)s_part;
                const int opair = jblk * 32 + pid;
#pragma unroll 8
                for (int g = part; g < CBLK; g += 8) {
                    u32 uv = spp[g * 10240 + opair];
                    a0 += bf2f((u16)(uv & 0xffff));
                    a1 += bf2f((u16)(uv >> 16));
                }
            }
            red[tid] = a0; red[NTHR + tid] = a1;
            __syncthreads();
            if (jtid < 32 && valid) {
                const int base = (tid < 256) ? 0 : 256;
                float s0 = 0.f, s1 = 0.f;
#pragma unroll
                for (int k = 0; k < 8; ++k) {
                    s0 += red[base + k * 32 + jtid];
                    s1 += red[NTHR + base + k * 32 + jtid];
                }
                float sq = s0 * s0 + s1 * s1;
                sq += __shfl_xor(sq, 1);   // 8 lanes = 16 elems of one (b,n)
                sq += __shfl_xor(sq, 2);
                sq += __shfl_xor(sq, 4);
                float fct = sq / ((1.f + sq) * sqrtf(sq));
                float ox = s0 * fct, oy = s1 * fct;
                const int oi = 2 * (jblk * 32 + jtid);
                if (itn == 0) {
                    *(float2*)(v0 + oi) = make_float2(ox, oy);
                } else if (itn == 1) {
                    float2 pv = *(const float2*)(v0 + oi);   // vs = v0 + v1
                    *(float2*)(vs + oi) = make_float2(ox + pv.x, oy + pv.y);
                } else {
                    *(float2*)(out + oi) = make_float2(ox, oy);
                }
            }
            __syncthreads();   // red[] reuse safety
        }
        if (itn < 2) {
            __threadfence();
            grid.sync();
        }
    }
}

// ---------------- fallback (previous pipeline, reads adapted to swizzled xb/wb)
template<int MODE>
__global__ __launch_bounds__(NTHR, 2) void k_pass(
        const u16* __restrict__ xb, const u16* __restrict__ wb,
        const float* __restrict__ vprev, u16* __restrict__ s_part)
{
    __shared__ u16 xt[128 * XS];
    __shared__ u16 wt[F_ * WS];
    const int tid = threadIdx.x, blk = blockIdx.x;
    const int L = tid & 63, wv = tid >> 6;
    const int q = L >> 4, col = L & 15;
    const int b = wv * 16 + col;
    const int qs = (q ^ ((col >> 1) & 3)) * 8;
    const int p0 = blk * 4;

    float4 vv[NC_];
    if (MODE != 0) {
#pragma unroll
        for (int n = 0; n < NC_; ++n)
            vv[n] = *(const float4*)(vprev + b * F_ + n * 16 + q * 4);
    }

    f32x4 s_acc[NC_];
#pragma unroll
    for (int n = 0; n < NC_; ++n) s_acc[n] = (f32x4){0.f, 0.f, 0.f, 0.f};

    uint4 r0, r1, r2;
    {
        const uint4* xg = (const uint4*)(xb + p0 * 4096);
        const uint4* wg = (const uint4*)(wb + p0 * 5120);
        r0 = xg[tid]; r1 = wg[tid];
        if (tid < 128) r2 = wg[tid + 512];
    }

#pragma unroll
    for (int pp = 0; pp < 4; ++pp) {
        __syncthreads();
        *(uint4*)&xt[(tid >> 2) * XS + (tid & 3) * 8] = r0;
        *(uint4*)&wt[(tid >> 2) * WS + (tid & 3) * 8] = r1;
        if (tid < 128)
            *(uint4*)&wt[(128 + (tid >> 2)) * WS + (tid & 3) * 8] = r2;
        if (pp + 1 < 4) {
            const uint4* xg = (const uint4*)(xb + (p0 + pp + 1) * 4096);
            const uint4* wg = (const uint4*)(wb + (p0 + pp + 1) * 5120);
            r0 = xg[tid]; r1 = wg[tid];
            if (tid < 128) r2 = wg[tid + 512];
        }
        __syncthreads();

        bf16x8 bfrag = *(const bf16x8*)&xt[b * XS + qs];
        if (MODE == 0) {
#pragma unroll
            for (int n = 0; n < NC_; ++n) {
                bf16x8 afrag = *(const bf16x8*)&wt[(n * 16 + col) * WS + qs];
                s_acc[n] = __builtin_amdgcn_mfma_f32_16x16x32_bf16(afrag, bfrag, s_acc[n], 0, 0, 0);
            }
        } else {
            float tt[NC_];
#pragma unroll
            for (int n = 0; n < NC_; ++n) {
                bf16x8 afrag = *(const bf16x8*)&wt[(n * 16 + col) * WS + qs];
                f32x4 z = {0.f, 0.f, 0.f, 0.f};
                f32x4 acc = __builtin_amdgcn_mfma_f32_16x16x32_bf16(afrag, bfrag, z, 0, 0, 0);
                float t = acc[0]*vv[n].x + acc[1]*vv[n].y + acc[2]*vv[n].z + acc[3]*vv[n].w;
                t += __shfl_xor(t, 16);
                t += __shfl_xor(t, 32);
                tt[n] = t;
            }
            float mx = tt[0];
#pragma unroll
            for (int n = 1; n < NC_; ++n) mx = fmaxf(mx, tt[n]);
            float den = 0.f;
#pragma unroll
            for (int n = 0; n < NC_; ++n) { tt[n] = __expf(tt[n] - mx); den += tt[n]; }
            float inv = 1.f / den;
#pragma unroll
            for (int n = 0; n < NC_; ++n) {
                bf16x8 afrag = *(const bf16x8*)&wt[(n * 16 + col) * WS + qs];
                f32x4 z = {0.f, 0.f, 0.f, 0.f};
                f32x4 acc = __builtin_amdgcn_mfma_f32_16x16x32_bf16(afrag, bfrag, z, 0, 0, 0);
                float cf = tt[n] * inv;
#pragma unroll
                for (int r = 0; r < 4; ++r) s_acc[n][r] += cf * acc[r];
            }
        }
    }

    u16* sp = s_part + blk * (B_ * F_);
    const float sc = (MODE == 0) ? 0.1f : 1.f;
#pragma unroll
    for (int n = 0; n < NC_; ++n) {
        u16 h[4] __attribute__((aligned(8)));
#pragma unroll
        for (int r = 0; r < 4; ++r) h[r] = f2bf(s_acc[n][r] * sc);
        *(ushort4*)(sp + b * F_ + n * 16 + q * 4) = *(const ushort4*)h;
    }
}

template<int ADD>
__global__ void k_red(const u16* __restrict__ s_part,
                      const float* __restrict__ vprev, float* __restrict__ vout) {
    __shared__ float r0s[256], r1s[256];
    const int tid = threadIdx.x, blk = blockIdx.x;
    const int pid = tid & 31, part = tid >> 5;
    const u32* sp = (const u32*)s_part;
    const int opair = blk * 32 + pid;
    float a0 = 0.f, a1 = 0.f;
#pragma unroll 8
    for (int g = part; g < GBLK; g += 8) {
        u32 uv = sp[g * 10240 + opair];
        a0 += bf2f((u16)(uv & 0xffff));
        a1 += bf2f((u16)(uv >> 16));
    }
    r0s[tid] = a0; r1s[tid] = a1;
    __syncthreads();
    if (tid < 32) {
        float s0 = 0.f, s1 = 0.f;
#pragma unroll
        for (int k = 0; k < 8; ++k) { s0 += r0s[k * 32 + tid]; s1 += r1s[k * 32 + tid]; }
        float sq = s0 * s0 + s1 * s1;
        sq += __shfl_xor(sq, 1);
        sq += __shfl_xor(sq, 2);
        sq += __shfl_xor(sq, 4);
        float fct = sq / ((1.f + sq) * sqrtf(sq));
        float2 o = make_float2(s0 * fct, s1 * fct);
        if (ADD) {
            float2 pv = *(const float2*)(vprev + 2 * (blk * 32 + tid));
            o.x += pv.x; o.y += pv.y;
        }
        *(float2*)(vout + 2 * (blk * 32 + tid)) = o;
    }
}

extern "C" void kernel_launch(void* const* d_in, const int* in_sizes, int n_in,
                              void* d_out, int out_size, void* d_ws, size_t ws_size,
                              hipStream_t stream) {
    const float* tensor = (const float*)d_in[0];
    const float* weight = (const float*)d_in[1];
    float* out = (float*)d_out;
    char* ws = (char*)d_ws;

    u16*   xb     = (u16*)(ws);                       // 16,777,216 B
    u16*   wb     = (u16*)(ws + 16777216);            // 20,971,520 B
    u16*   s_part = (u16*)(ws + 37748736);            // <= 20,971,520 B
    float* v0     = (float*)(ws + 58720256);          // 81,920 B
    float* vs     = (float*)(ws + 58802176);          // 81,920 B

    k_squash_x<<<4096, 256, 0, stream>>>(tensor, xb);
    k_wt<<<2048, 256, 0, stream>>>(weight, wb);

    void* args[6] = { (void*)&xb, (void*)&wb, (void*)&s_part,
                      (void*)&v0, (void*)&vs, (void*)&out };
    hipError_t err = hipLaunchCooperativeKernel((const void*)k_route, dim3(CBLK),
                                                dim3(NTHR), args, 0, stream);
    if (err != hipSuccess) {
        (void)hipGetLastError();   // clear sticky error; run previous pipeline
        k_pass<0><<<GBLK, NTHR, 0, stream>>>(xb, wb, nullptr, s_part);
        k_red<0><<<320, 256, 0, stream>>>(s_part, nullptr, v0);
        k_pass<1><<<GBLK, NTHR, 0, stream>>>(xb, wb, v0, s_part);
        k_red<1><<<320, 256, 0, stream>>>(s_part, v0, vs);
        k_pass<2><<<GBLK, NTHR, 0, stream>>>(xb, wb, vs, s_part);
        k_red<0><<<320, 256, 0, stream>>>(s_part, nullptr, out);
    }
}

// Round 2
// 242.773 us; speedup vs baseline: 2.4835x; 2.4835x over previous
//
#include <hip/hip_runtime.h>

typedef unsigned short u16;
typedef unsigned int u32;
typedef __attribute__((ext_vector_type(8))) short bf16x8;
typedef __attribute__((ext_vector_type(4))) float f32x4;

#define B_   128
#define P_   2048
#define NC_  10
#define F_   160      // NC*CLO
#define NBLK 512      // k_pass blocks: 2 per CU
#define PPB  4        // p-tiles per block
#define NTHR 512

// async global->LDS, 16B per lane (linear dest, per-lane source)
#define GLL(g, l) __builtin_amdgcn_global_load_lds( \
    (const __attribute__((address_space(1))) void*)(g), \
    (__attribute__((address_space(3))) void*)(l), 16, 0, 0)

__device__ __forceinline__ u16 f2bf(float f) {
    union { float f; unsigned u; } v; v.f = f;
    unsigned r = v.u + 0x7FFFu + ((v.u >> 16) & 1u);   // RNE
    return (u16)(r >> 16);
}
__device__ __forceinline__ float bf2f(u16 h) {
    union { unsigned u; float f; } v; v.u = ((unsigned)h) << 16;
    return v.f;
}

// Fused prep. Blocks 0..4095: squash along NP=32, cast bf16, write
// xb[p][b][chunk] with chunk XOR-swizzle (slot' = slot ^ ((b>>1)&3)) so the
// consumer's unpadded LDS image is conflict-free on ds_read_b128 (validated
// round 1: SQ_LDS_BANK_CONFLICT=0). Blocks 4096..6143: weight[p][k][f] fp32 ->
// wb[p][f][k] bf16 transpose via LDS, same chunk swizzle.
__global__ void k_prep(const float* __restrict__ t, const float* __restrict__ w,
                       u16* __restrict__ xb, u16* __restrict__ wb) {
    __shared__ u16 wl[32 * F_];
    const int tid = threadIdx.x;
    if (blockIdx.x < 4096) {
        int g = blockIdx.x * 256 + tid;
        int pair = g >> 2, sub = g & 3;
        int p = pair & 2047, b = pair >> 11;
        const float4* tg = (const float4*)t;
        int fi = pair * 8 + sub * 2;
        float4 va = tg[fi], vb = tg[fi + 1];
        float ss = va.x*va.x + va.y*va.y + va.z*va.z + va.w*va.w
                 + vb.x*vb.x + vb.y*vb.y + vb.z*vb.z + vb.w*vb.w;
        ss += __shfl_xor(ss, 1);      // quad holds the full 32-elem sum
        ss += __shfl_xor(ss, 2);
        float fct = ss / ((1.f + ss) * sqrtf(ss));
        u16 h[8] __attribute__((aligned(16)));
        h[0]=f2bf(va.x*fct); h[1]=f2bf(va.y*fct); h[2]=f2bf(va.z*fct); h[3]=f2bf(va.w*fct);
        h[4]=f2bf(vb.x*fct); h[5]=f2bf(vb.y*fct); h[6]=f2bf(vb.z*fct); h[7]=f2bf(vb.w*fct);
        int sw = sub ^ ((b >> 1) & 3);
        *(uint4*)(xb + (p * 128 + b) * 32 + sw * 8) = *(const uint4*)h;
    } else {
        int p = blockIdx.x - 4096;
        const float4* wp = (const float4*)(w + p * 32 * F_);
        for (int e4 = tid; e4 < 1280; e4 += 256) {
            float4 v = wp[e4];
            u16 h[4] __attribute__((aligned(8)));
            h[0]=f2bf(v.x); h[1]=f2bf(v.y); h[2]=f2bf(v.z); h[3]=f2bf(v.w);
            *(ushort4*)(wl + e4 * 4) = *(const ushort4*)h;
        }
        __syncthreads();
        u16* wo = wb + p * F_ * 32;
        for (int sid = tid; sid < 640; sid += 256) {
            int f = sid >> 2, k0 = (sid & 3) << 3;
            u16 tmp[8] __attribute__((aligned(16)));
#pragma unroll
            for (int j = 0; j < 8; ++j) tmp[j] = wl[(k0 + j) * F_ + f];
            int sw = (sid & 3) ^ ((f >> 1) & 3);
            *(uint4*)(wo + f * 32 + sw * 8) = *(const uint4*)tmp;
        }
    }
}

// One routing pass. MODE 0: c=0.1 uniform (MFMA-chained). MODE>=1: logits are
// t = u.vprev (vprev = v0 for pass 1, v0+v1 for pass 2), softmax over n,
// weighted sum. Staging: global_load_lds dwordx4 into double-buffered linear
// LDS; one __syncthreads per tile (its vmcnt/lgkm drain IS the load wait).
template<int MODE>
__global__ __launch_bounds__(NTHR, 4) void k_pass(
        const u16* __restrict__ xb, const u16* __restrict__ wb,
        const float* __restrict__ vprev, u16* __restrict__ s_part)
{
    __shared__ u16 xt[2][4096];    // 2 x 8192 B
    __shared__ u16 wt[2][5120];    // 2 x 10240 B
    const int tid = threadIdx.x, blk = blockIdx.x;
    const int L = tid & 63, wv = tid >> 6;
    const int q = L >> 4, col = L & 15;
    const int b = wv * 16 + col;
    const int qs = (q ^ ((col >> 1) & 3)) * 8;   // swizzled k-slot (shorts)
    const int p0 = blk * PPB;

    float4 vv[NC_];
    if (MODE != 0) {
#pragma unroll
        for (int n = 0; n < NC_; ++n)
            vv[n] = *(const float4*)(vprev + b * F_ + n * 16 + q * 4);
    }

    f32x4 s_acc[NC_];
#pragma unroll
    for (int n = 0; n < NC_; ++n) s_acc[n] = (f32x4){0.f, 0.f, 0.f, 0.f};

    {   // stage tile 0
        const u16* xg = xb + (size_t)p0 * 4096;
        const u16* wg = wb + (size_t)p0 * 5120;
        GLL(xg + tid * 8, &xt[0][tid * 8]);
        GLL(wg + tid * 8, &wt[0][tid * 8]);
        if (tid < 128) GLL(wg + 4096 + tid * 8, &wt[0][4096 + tid * 8]);
    }
    __syncthreads();

    int cur = 0;
#pragma unroll
    for (int pp = 0; pp < PPB; ++pp) {
        if (pp + 1 < PPB) {    // issue next tile's loads; they fly during compute
            const u16* xg = xb + (size_t)(p0 + pp + 1) * 4096;
            const u16* wg = wb + (size_t)(p0 + pp + 1) * 5120;
            GLL(xg + tid * 8, &xt[cur ^ 1][tid * 8]);
            GLL(wg + tid * 8, &wt[cur ^ 1][tid * 8]);
            if (tid < 128) GLL(wg + 4096 + tid * 8, &wt[cur ^ 1][4096 + tid * 8]);
        }

        bf16x8 bfrag = *(const bf16x8*)&xt[cur][b * 32 + qs];   // x[b][k=q*8+j]
        if (MODE == 0) {
#pragma unroll
            for (int n = 0; n < NC_; ++n) {
                bf16x8 afrag = *(const bf16x8*)&wt[cur][(n * 16 + col) * 32 + qs];
                s_acc[n] = __builtin_amdgcn_mfma_f32_16x16x32_bf16(afrag, bfrag, s_acc[n], 0, 0, 0);
            }
        } else {
            float tt[NC_];
#pragma unroll
            for (int n = 0; n < NC_; ++n) {
                bf16x8 afrag = *(const bf16x8*)&wt[cur][(n * 16 + col) * 32 + qs];
                f32x4 z = {0.f, 0.f, 0.f, 0.f};
                f32x4 acc = __builtin_amdgcn_mfma_f32_16x16x32_bf16(afrag, bfrag, z, 0, 0, 0);
                float t = acc[0]*vv[n].x + acc[1]*vv[n].y + acc[2]*vv[n].z + acc[3]*vv[n].w;
                t += __shfl_xor(t, 16);   // full 16-elem dot over k'
                t += __shfl_xor(t, 32);
                tt[n] = t;
            }
            float mx = tt[0];
#pragma unroll
            for (int n = 1; n < NC_; ++n) mx = fmaxf(mx, tt[n]);
            float den = 0.f;
#pragma unroll
            for (int n = 0; n < NC_; ++n) { tt[n] = __expf(tt[n] - mx); den += tt[n]; }
            float inv = 1.f / den;
#pragma unroll
            for (int n = 0; n < NC_; ++n) {
                bf16x8 afrag = *(const bf16x8*)&wt[cur][(n * 16 + col) * 32 + qs];
                f32x4 z = {0.f, 0.f, 0.f, 0.f};
                f32x4 acc = __builtin_amdgcn_mfma_f32_16x16x32_bf16(afrag, bfrag, z, 0, 0, 0);
                float cf = tt[n] * inv;
#pragma unroll
                for (int r = 0; r < 4; ++r) s_acc[n][r] += cf * acc[r];
            }
        }
        __syncthreads();      // drains next-tile loads + protects buffer reuse
        cur ^= 1;
    }

    u16* sp = s_part + blk * (B_ * F_);
    const float sc = (MODE == 0) ? 0.1f : 1.f;
#pragma unroll
    for (int n = 0; n < NC_; ++n) {
        u16 h[4] __attribute__((aligned(8)));
#pragma unroll
        for (int r = 0; r < 4; ++r) h[r] = f2bf(s_acc[n][r] * sc);
        *(ushort4*)(sp + b * F_ + n * 16 + q * 4) = *(const ushort4*)h;
    }
}

// Sum bf16 partials over NBLK groups (uint4 = one full (b,n) 16-elem row per
// load), squash along CLO=16. ADD: add vprev (produces v0+v1 for next logits).
template<int ADD>
__global__ void k_red(const u16* __restrict__ s_part,
                      const float* __restrict__ vprev, float* __restrict__ vout) {
    __shared__ float red[32 * 66];    // padded: 2-way max on store/load
    const int tid = threadIdx.x, blk = blockIdx.x;
    const int pid = tid & 7, part = tid >> 3;     // 8 uint4 lanes x 32 parts
    const uint4* sp4 = (const uint4*)s_part;      // 2560 uint4 per group
    const int base = blk * 8 + pid;
    float a[8];
#pragma unroll
    for (int j = 0; j < 8; ++j) a[j] = 0.f;
#pragma unroll
    for (int g = part; g < NBLK; g += 32) {
        uint4 uv = sp4[g * 2560 + base];
        a[0] += bf2f((u16)(uv.x & 0xffff)); a[1] += bf2f((u16)(uv.x >> 16));
        a[2] += bf2f((u16)(uv.y & 0xffff)); a[3] += bf2f((u16)(uv.y >> 16));
        a[4] += bf2f((u16)(uv.z & 0xffff)); a[5] += bf2f((u16)(uv.z >> 16));
        a[6] += bf2f((u16)(uv.w & 0xffff)); a[7] += bf2f((u16)(uv.w >> 16));
    }
#pragma unroll
    for (int j = 0; j < 8; ++j) red[part * 66 + pid * 8 + j] = a[j];
    __syncthreads();
    if (tid < 32) {
        float s0 = 0.f, s1 = 0.f;
#pragma unroll
        for (int k = 0; k < 32; ++k) {
            s0 += red[k * 66 + tid * 2];
            s1 += red[k * 66 + tid * 2 + 1];
        }
        float sq = s0 * s0 + s1 * s1;
        sq += __shfl_xor(sq, 1);    // 8 lanes = 16 elems of one (b,n)
        sq += __shfl_xor(sq, 2);
        sq += __shfl_xor(sq, 4);
        float fct = sq / ((1.f + sq) * sqrtf(sq));
        float2 o = make_float2(s0 * fct, s1 * fct);
        if (ADD) {
            float2 pv = *(const float2*)(vprev + 2 * (blk * 32 + tid));
            o.x += pv.x; o.y += pv.y;
        }
        *(float2*)(vout + 2 * (blk * 32 + tid)) = o;
    }
}

extern "C" void kernel_launch(void* const* d_in, const int* in_sizes, int n_in,
                              void* d_out, int out_size, void* d_ws, size_t ws_size,
                              hipStream_t stream) {
    const float* tensor = (const float*)d_in[0];
    const float* weight = (const float*)d_in[1];
    float* out = (float*)d_out;
    char* ws = (char*)d_ws;

    u16*   xb     = (u16*)(ws);                       // 16,777,216 B
    u16*   wb     = (u16*)(ws + 16777216);            // 20,971,520 B
    u16*   s_part = (u16*)(ws + 37748736);            // 512*20480*2 = 20,971,520 B
    float* v0     = (float*)(ws + 58720256);          // 81,920 B
    float* vs     = (float*)(ws + 58802176);          // 81,920 B (v0 + v1)

    k_prep<<<6144, 256, 0, stream>>>(tensor, weight, xb, wb);

    k_pass<0><<<NBLK, NTHR, 0, stream>>>(xb, wb, nullptr, s_part);
    k_red<0><<<320, 256, 0, stream>>>(s_part, nullptr, v0);
    k_pass<1><<<NBLK, NTHR, 0, stream>>>(xb, wb, v0, s_part);
    k_red<1><<<320, 256, 0, stream>>>(s_part, v0, vs);
    k_pass<2><<<NBLK, NTHR, 0, stream>>>(xb, wb, vs, s_part);
    k_red<0><<<320, 256, 0, stream>>>(s_part, nullptr, out);
}

// Round 3
// 240.488 us; speedup vs baseline: 2.5071x; 1.0095x over previous
//
#include <hip/hip_runtime.h>

typedef unsigned short u16;
typedef unsigned int u32;
typedef __attribute__((ext_vector_type(8))) short bf16x8;
typedef __attribute__((ext_vector_type(4))) float f32x4;

#define B_   128
#define P_   2048
#define NC_  10
#define F_   160      // NC*CLO
#define NBLK 256      // k_pass blocks: 1 per CU
#define PPB  8        // p-tiles per block
#define NTHR 512

// async global->LDS (linear dest = wave-uniform base + lane*size)
#define GLL16(g, l) __builtin_amdgcn_global_load_lds( \
    (const __attribute__((address_space(1))) void*)(g), \
    (__attribute__((address_space(3))) void*)(l), 16, 0, 0)
#define GLL4(g, l) __builtin_amdgcn_global_load_lds( \
    (const __attribute__((address_space(1))) void*)(g), \
    (__attribute__((address_space(3))) void*)(l), 4, 0, 0)

__device__ __forceinline__ u16 f2bf(float f) {
    union { float f; unsigned u; } v; v.f = f;
    unsigned r = v.u + 0x7FFFu + ((v.u >> 16) & 1u);   // RNE
    return (u16)(r >> 16);
}
__device__ __forceinline__ float bf2f(u16 h) {
    union { unsigned u; float f; } v; v.u = ((unsigned)h) << 16;
    return v.f;
}

// Fused prep (unchanged, hardware-validated: SQ_LDS_BANK_CONFLICT=0).
// Blocks 0..4095: squash along NP=32, bf16-cast, write xb[p][b][chunk] with
// chunk XOR-swizzle (slot' = slot ^ ((b>>1)&3)). Blocks 4096..6143:
// weight[p][k][f] fp32 -> wb[p][f][k] bf16 transpose via LDS, same swizzle.
__global__ void k_prep(const float* __restrict__ t, const float* __restrict__ w,
                       u16* __restrict__ xb, u16* __restrict__ wb) {
    __shared__ u16 wl[32 * F_];
    const int tid = threadIdx.x;
    if (blockIdx.x < 4096) {
        int g = blockIdx.x * 256 + tid;
        int pair = g >> 2, sub = g & 3;
        int p = pair & 2047, b = pair >> 11;
        const float4* tg = (const float4*)t;
        int fi = pair * 8 + sub * 2;
        float4 va = tg[fi], vb = tg[fi + 1];
        float ss = va.x*va.x + va.y*va.y + va.z*va.z + va.w*va.w
                 + vb.x*vb.x + vb.y*vb.y + vb.z*vb.z + vb.w*vb.w;
        ss += __shfl_xor(ss, 1);      // quad holds the full 32-elem sum
        ss += __shfl_xor(ss, 2);
        float fct = ss / ((1.f + ss) * sqrtf(ss));
        u16 h[8] __attribute__((aligned(16)));
        h[0]=f2bf(va.x*fct); h[1]=f2bf(va.y*fct); h[2]=f2bf(va.z*fct); h[3]=f2bf(va.w*fct);
        h[4]=f2bf(vb.x*fct); h[5]=f2bf(vb.y*fct); h[6]=f2bf(vb.z*fct); h[7]=f2bf(vb.w*fct);
        int sw = sub ^ ((b >> 1) & 3);
        *(uint4*)(xb + (p * 128 + b) * 32 + sw * 8) = *(const uint4*)h;
    } else {
        int p = blockIdx.x - 4096;
        const float4* wp = (const float4*)(w + p * 32 * F_);
        for (int e4 = tid; e4 < 1280; e4 += 256) {
            float4 v = wp[e4];
            u16 h[4] __attribute__((aligned(8)));
            h[0]=f2bf(v.x); h[1]=f2bf(v.y); h[2]=f2bf(v.z); h[3]=f2bf(v.w);
            *(ushort4*)(wl + e4 * 4) = *(const ushort4*)h;
        }
        __syncthreads();
        u16* wo = wb + p * F_ * 32;
        for (int sid = tid; sid < 640; sid += 256) {
            int f = sid >> 2, k0 = (sid & 3) << 3;
            u16 tmp[8] __attribute__((aligned(16)));
#pragma unroll
            for (int j = 0; j < 8; ++j) tmp[j] = wl[(k0 + j) * F_ + f];
            int sw = (sid & 3) ^ ((f >> 1) & 3);
            *(uint4*)(wo + f * 32 + sw * 8) = *(const uint4*)tmp;
        }
    }
}

// One routing pass. 3-buffer LDS pipeline, 2 tiles prefetched ahead, counted
// s_waitcnt vmcnt(6/3/0) + raw s_barrier (loads stay in flight across
// barriers). Every wave issues exactly 3 GLL per tile (16B+16B+4B) so counts
// are wave-uniform. Partial output s_part[blk][n][b][k]: each wave store is
// 512 contiguous bytes (4 full 128B lines) -> no partial-line RMW.
template<int MODE>
__global__ __launch_bounds__(NTHR, 2) void k_pass(
        const u16* __restrict__ xb, const u16* __restrict__ wb,
        const float* __restrict__ vprev, u16* __restrict__ s_part)
{
    __shared__ u16 xt[3][4096];    // 3 x 8 KB
    __shared__ u16 wt[3][5120];    // 3 x 10 KB   (total 54 KB)
    const int tid = threadIdx.x, blk = blockIdx.x;
    const int L = tid & 63, wv = tid >> 6;
    const int q = L >> 4, col = L & 15;
    const int b = wv * 16 + col;
    const int qs = (q ^ ((col >> 1) & 3)) * 8;   // swizzled k-slot (shorts)
    const int p0 = blk * PPB;

    float4 vv[NC_];
    if (MODE != 0) {
#pragma unroll
        for (int n = 0; n < NC_; ++n)
            vv[n] = *(const float4*)(vprev + b * F_ + n * 16 + q * 4);
    }

    f32x4 s_acc[NC_];
#pragma unroll
    for (int n = 0; n < NC_; ++n) s_acc[n] = (f32x4){0.f, 0.f, 0.f, 0.f};

#define STAGE(t, s) do { \
        const u16* xg_ = xb + (size_t)(p0 + (t)) * 4096; \
        const u16* wg_ = wb + (size_t)(p0 + (t)) * 5120; \
        GLL16(xg_ + tid * 8, &xt[s][tid * 8]); \
        GLL16(wg_ + tid * 8, &wt[s][tid * 8]); \
        GLL4 (wg_ + 4096 + tid * 2, &wt[s][4096 + tid * 2]); \
    } while (0)

    STAGE(0, 0);
    STAGE(1, 1);

#pragma unroll
    for (int t = 0; t < PPB; ++t) {
        const int s = t % 3;
        if (t + 2 < PPB) STAGE(t + 2, (t + 2) % 3);
        // wait until tile t's 3 loads land; leave t+1/t+2's in flight
        if (t + 2 < PPB)      asm volatile("s_waitcnt vmcnt(6)" ::: "memory");
        else if (t + 1 < PPB) asm volatile("s_waitcnt vmcnt(3)" ::: "memory");
        else                  asm volatile("s_waitcnt vmcnt(0)" ::: "memory");
        __builtin_amdgcn_s_barrier();      // tile t visible to all waves

        bf16x8 bfrag = *(const bf16x8*)&xt[s][b * 32 + qs];   // x[b][k=q*8+j]
        if (MODE == 0) {
#pragma unroll
            for (int n = 0; n < NC_; ++n) {
                bf16x8 afrag = *(const bf16x8*)&wt[s][(n * 16 + col) * 32 + qs];
                s_acc[n] = __builtin_amdgcn_mfma_f32_16x16x32_bf16(afrag, bfrag, s_acc[n], 0, 0, 0);
            }
        } else {
            float tt[NC_];
#pragma unroll
            for (int n = 0; n < NC_; ++n) {
                bf16x8 afrag = *(const bf16x8*)&wt[s][(n * 16 + col) * 32 + qs];
                f32x4 z = {0.f, 0.f, 0.f, 0.f};
                f32x4 acc = __builtin_amdgcn_mfma_f32_16x16x32_bf16(afrag, bfrag, z, 0, 0, 0);
                float tv = acc[0]*vv[n].x + acc[1]*vv[n].y + acc[2]*vv[n].z + acc[3]*vv[n].w;
                tv += __shfl_xor(tv, 16);   // full 16-elem dot over k'
                tv += __shfl_xor(tv, 32);
                tt[n] = tv;
            }
            float mx = tt[0];
#pragma unroll
            for (int n = 1; n < NC_; ++n) mx = fmaxf(mx, tt[n]);
            float den = 0.f;
#pragma unroll
            for (int n = 0; n < NC_; ++n) { tt[n] = __expf(tt[n] - mx); den += tt[n]; }
            float inv = 1.f / den;
#pragma unroll
            for (int n = 0; n < NC_; ++n) {
                bf16x8 afrag = *(const bf16x8*)&wt[s][(n * 16 + col) * 32 + qs];
                f32x4 z = {0.f, 0.f, 0.f, 0.f};
                f32x4 acc = __builtin_amdgcn_mfma_f32_16x16x32_bf16(afrag, bfrag, z, 0, 0, 0);
                float cf = tt[n] * inv;
#pragma unroll
                for (int r = 0; r < 4; ++r) s_acc[n][r] += cf * acc[r];
            }
        }
        __builtin_amdgcn_s_barrier();      // all reads done before buf reuse
    }
#undef STAGE

    // n-major partial store: wave wv writes bytes [n*4096 + wv*512, +512)
    u16* sp = s_part + blk * (B_ * F_);
    const float sc = (MODE == 0) ? 0.1f : 1.f;
#pragma unroll
    for (int n = 0; n < NC_; ++n) {
        u16 h[4] __attribute__((aligned(8)));
#pragma unroll
        for (int r = 0; r < 4; ++r) h[r] = f2bf(s_acc[n][r] * sc);
        *(ushort4*)(sp + n * 2048 + b * 16 + q * 4) = *(const ushort4*)h;
    }
}

// Sum bf16 partials over NBLK groups (n-major layout), squash along CLO=16.
// ADD: add vprev (produces v0+v1 for the next pass's logits).
template<int ADD>
__global__ void k_red(const u16* __restrict__ s_part,
                      const float* __restrict__ vprev, float* __restrict__ vout) {
    __shared__ float red[32 * 66];
    const int tid = threadIdx.x, blk = blockIdx.x;
    const int pid = tid & 7, part = tid >> 3;     // 8 uint4 lanes x 32 parts
    const uint4* sp4 = (const uint4*)s_part;      // 2560 uint4 per group
    const int base = blk * 8 + pid;               // uint4 column 0..2559
    float a[8];
#pragma unroll
    for (int j = 0; j < 8; ++j) a[j] = 0.f;
#pragma unroll
    for (int g = part; g < NBLK; g += 32) {
        uint4 uv = sp4[g * 2560 + base];
        a[0] += bf2f((u16)(uv.x & 0xffff)); a[1] += bf2f((u16)(uv.x >> 16));
        a[2] += bf2f((u16)(uv.y & 0xffff)); a[3] += bf2f((u16)(uv.y >> 16));
        a[4] += bf2f((u16)(uv.z & 0xffff)); a[5] += bf2f((u16)(uv.z >> 16));
        a[6] += bf2f((u16)(uv.w & 0xffff)); a[7] += bf2f((u16)(uv.w >> 16));
    }
#pragma unroll
    for (int j = 0; j < 8; ++j) red[part * 66 + pid * 8 + j] = a[j];
    __syncthreads();
    if (tid < 32) {
        float s0 = 0.f, s1 = 0.f;
#pragma unroll
        for (int k = 0; k < 32; ++k) {
            s0 += red[k * 66 + tid * 2];
            s1 += red[k * 66 + tid * 2 + 1];
        }
        float sq = s0 * s0 + s1 * s1;
        sq += __shfl_xor(sq, 1);    // 8 lanes = 16 elems of one (b,n) row
        sq += __shfl_xor(sq, 2);
        sq += __shfl_xor(sq, 4);
        float fct = sq / ((1.f + sq) * sqrtf(sq));
        // remap n-major partial index -> b-major output index
        const int i = blk * 8 + (tid >> 2);       // uint4 column of this pair
        const int n = i >> 8, bb = (i & 255) >> 1, hh = i & 1;
        const int f0 = bb * 160 + n * 16 + hh * 8 + 2 * (tid & 3);
        float2 o = make_float2(s0 * fct, s1 * fct);
        if (ADD) {
            float2 pv = *(const float2*)(vprev + f0);
            o.x += pv.x; o.y += pv.y;
        }
        *(float2*)(vout + f0) = o;
    }
}

extern "C" void kernel_launch(void* const* d_in, const int* in_sizes, int n_in,
                              void* d_out, int out_size, void* d_ws, size_t ws_size,
                              hipStream_t stream) {
    const float* tensor = (const float*)d_in[0];
    const float* weight = (const float*)d_in[1];
    float* out = (float*)d_out;
    char* ws = (char*)d_ws;

    u16*   xb     = (u16*)(ws);                       // 16,777,216 B
    u16*   wb     = (u16*)(ws + 16777216);            // 20,971,520 B
    u16*   s_part = (u16*)(ws + 37748736);            // 256*40960 = 10,485,760 B
    float* v0     = (float*)(ws + 58720256);          // 81,920 B
    float* vs     = (float*)(ws + 58802176);          // 81,920 B (v0 + v1)

    k_prep<<<6144, 256, 0, stream>>>(tensor, weight, xb, wb);

    k_pass<0><<<NBLK, NTHR, 0, stream>>>(xb, wb, nullptr, s_part);
    k_red<0><<<320, 256, 0, stream>>>(s_part, nullptr, v0);
    k_pass<1><<<NBLK, NTHR, 0, stream>>>(xb, wb, v0, s_part);
    k_red<1><<<320, 256, 0, stream>>>(s_part, v0, vs);
    k_pass<2><<<NBLK, NTHR, 0, stream>>>(xb, wb, vs, s_part);
    k_red<0><<<320, 256, 0, stream>>>(s_part, nullptr, out);
}

// Round 4
// 176.374 us; speedup vs baseline: 3.4184x; 1.3635x over previous
//
#include <hip/hip_runtime.h>

typedef unsigned short u16;
typedef unsigned int u32;
typedef __attribute__((ext_vector_type(8))) short bf16x8;
typedef __attribute__((ext_vector_type(4))) float f32x4;

#define B_   128
#define P_   2048
#define NC_  10
#define F_   160      // NC*CLO
#define NBLK 512      // k_pass blocks: 2 per CU (proven best occupancy)
#define PPB  4        // p-tiles per block
#define NTHR 512

__device__ __forceinline__ u16 f2bf(float f) {
    union { float f; unsigned u; } v; v.f = f;
    unsigned r = v.u + 0x7FFFu + ((v.u >> 16) & 1u);   // RNE
    return (u16)(r >> 16);
}
__device__ __forceinline__ float bf2f(u16 h) {
    union { unsigned u; float f; } v; v.u = ((unsigned)h) << 16;
    return v.f;
}

// Fused prep (hardware-validated; SQ_LDS_BANK_CONFLICT=0 downstream).
// Blocks 0..4095: squash along NP=32, bf16-cast, write xb[p][b][chunk] with
// chunk XOR-swizzle (slot' = slot ^ ((b>>1)&3)). Blocks 4096..6143:
// weight[p][k][f] fp32 -> wb[p][f][k] bf16 transpose via LDS, same swizzle.
__global__ void k_prep(const float* __restrict__ t, const float* __restrict__ w,
                       u16* __restrict__ xb, u16* __restrict__ wb) {
    __shared__ u16 wl[32 * F_];
    const int tid = threadIdx.x;
    if (blockIdx.x < 4096) {
        int g = blockIdx.x * 256 + tid;
        int pair = g >> 2, sub = g & 3;
        int p = pair & 2047, b = pair >> 11;
        const float4* tg = (const float4*)t;
        int fi = pair * 8 + sub * 2;
        float4 va = tg[fi], vb = tg[fi + 1];
        float ss = va.x*va.x + va.y*va.y + va.z*va.z + va.w*va.w
                 + vb.x*vb.x + vb.y*vb.y + vb.z*vb.z + vb.w*vb.w;
        ss += __shfl_xor(ss, 1);      // quad holds the full 32-elem sum
        ss += __shfl_xor(ss, 2);
        float fct = ss / ((1.f + ss) * sqrtf(ss));
        u16 h[8] __attribute__((aligned(16)));
        h[0]=f2bf(va.x*fct); h[1]=f2bf(va.y*fct); h[2]=f2bf(va.z*fct); h[3]=f2bf(va.w*fct);
        h[4]=f2bf(vb.x*fct); h[5]=f2bf(vb.y*fct); h[6]=f2bf(vb.z*fct); h[7]=f2bf(vb.w*fct);
        int sw = sub ^ ((b >> 1) & 3);
        *(uint4*)(xb + (p * 128 + b) * 32 + sw * 8) = *(const uint4*)h;
    } else {
        int p = blockIdx.x - 4096;
        const float4* wp = (const float4*)(w + p * 32 * F_);
        for (int e4 = tid; e4 < 1280; e4 += 256) {
            float4 v = wp[e4];
            u16 h[4] __attribute__((aligned(8)));
            h[0]=f2bf(v.x); h[1]=f2bf(v.y); h[2]=f2bf(v.z); h[3]=f2bf(v.w);
            *(ushort4*)(wl + e4 * 4) = *(const ushort4*)h;
        }
        __syncthreads();
        u16* wo = wb + p * F_ * 32;
        for (int sid = tid; sid < 640; sid += 256) {
            int f = sid >> 2, k0 = (sid & 3) << 3;
            u16 tmp[8] __attribute__((aligned(16)));
#pragma unroll
            for (int j = 0; j < 8; ++j) tmp[j] = wl[(k0 + j) * F_ + f];
            int sw = (sid & 3) ^ ((f >> 1) & 3);
            *(uint4*)(wo + f * 32 + sw * 8) = *(const uint4*)tmp;
        }
    }
}

// One routing pass -- EXACT round-0 structure (reg-staged double-buffered LDS,
// two barriers per tile, 2 blocks/CU, 128-VGPR budget). Only deltas from the
// proven 174us version: unpadded swizzled LDS (linear uint4 staging writes)
// and the n-major full-line partial store.
// MODE 0: c=0.1 uniform (MFMA-chained). MODE>=1: logits t = u.vprev (vprev =
// v0 for pass 1, v0+v1 for pass 2 -- bias eliminated algebraically), softmax
// over n, weighted sum.
template<int MODE>
__global__ __launch_bounds__(NTHR, 2) void k_pass(
        const u16* __restrict__ xb, const u16* __restrict__ wb,
        const float* __restrict__ vprev, u16* __restrict__ s_part)
{
    __shared__ u16 xt[2][4096];    // 2 x 8 KB
    __shared__ u16 wt[2][5120];    // 2 x 10 KB
    const int tid = threadIdx.x, blk = blockIdx.x;
    const int L = tid & 63, wv = tid >> 6;
    const int q = L >> 4, col = L & 15;
    const int b = wv * 16 + col;
    const int qs = (q ^ ((col >> 1) & 3)) * 8;   // swizzled k-slot (shorts)
    const int p0 = blk * PPB;

    float4 vv[NC_];
    if (MODE != 0) {
#pragma unroll
        for (int n = 0; n < NC_; ++n)
            vv[n] = *(const float4*)(vprev + b * F_ + n * 16 + q * 4);
    }

    f32x4 s_acc[NC_];
#pragma unroll
    for (int n = 0; n < NC_; ++n) s_acc[n] = (f32x4){0.f, 0.f, 0.f, 0.f};

    // prefetch registers: x tile = 512 uint4, w tile = 640 uint4
    uint4 r0, r1, r2;
    {
        const uint4* xg = (const uint4*)(xb + (size_t)p0 * 4096);
        const uint4* wg = (const uint4*)(wb + (size_t)p0 * 5120);
        r0 = xg[tid]; r1 = wg[tid];
        if (tid < 128) r2 = wg[tid + 512];
    }

    int cur = 0;
#pragma unroll
    for (int pp = 0; pp < PPB; ++pp) {
        __syncthreads();          // previous tile fully consumed
        ((uint4*)xt[cur])[tid] = r0;
        ((uint4*)wt[cur])[tid] = r1;
        if (tid < 128) ((uint4*)wt[cur])[512 + tid] = r2;
        if (pp + 1 < PPB) {       // next tile's loads fly during compute
            const uint4* xg = (const uint4*)(xb + (size_t)(p0 + pp + 1) * 4096);
            const uint4* wg = (const uint4*)(wb + (size_t)(p0 + pp + 1) * 5120);
            r0 = xg[tid]; r1 = wg[tid];
            if (tid < 128) r2 = wg[tid + 512];
        }
        __syncthreads();          // tile visible

        bf16x8 bfrag = *(const bf16x8*)&xt[cur][b * 32 + qs];   // x[b][k=q*8+j]
        if (MODE == 0) {
#pragma unroll
            for (int n = 0; n < NC_; ++n) {
                bf16x8 afrag = *(const bf16x8*)&wt[cur][(n * 16 + col) * 32 + qs];
                s_acc[n] = __builtin_amdgcn_mfma_f32_16x16x32_bf16(afrag, bfrag, s_acc[n], 0, 0, 0);
            }
        } else {
            float tt[NC_];
#pragma unroll
            for (int n = 0; n < NC_; ++n) {
                bf16x8 afrag = *(const bf16x8*)&wt[cur][(n * 16 + col) * 32 + qs];
                f32x4 z = {0.f, 0.f, 0.f, 0.f};
                f32x4 acc = __builtin_amdgcn_mfma_f32_16x16x32_bf16(afrag, bfrag, z, 0, 0, 0);
                float tv = acc[0]*vv[n].x + acc[1]*vv[n].y + acc[2]*vv[n].z + acc[3]*vv[n].w;
                tv += __shfl_xor(tv, 16);   // full 16-elem dot over k'
                tv += __shfl_xor(tv, 32);
                tt[n] = tv;
            }
            float mx = tt[0];
#pragma unroll
            for (int n = 1; n < NC_; ++n) mx = fmaxf(mx, tt[n]);
            float den = 0.f;
#pragma unroll
            for (int n = 0; n < NC_; ++n) { tt[n] = __expf(tt[n] - mx); den += tt[n]; }
            float inv = 1.f / den;
#pragma unroll
            for (int n = 0; n < NC_; ++n) {
                bf16x8 afrag = *(const bf16x8*)&wt[cur][(n * 16 + col) * 32 + qs];
                f32x4 z = {0.f, 0.f, 0.f, 0.f};
                f32x4 acc = __builtin_amdgcn_mfma_f32_16x16x32_bf16(afrag, bfrag, z, 0, 0, 0);
                float cf = tt[n] * inv;
#pragma unroll
                for (int r = 0; r < 4; ++r) s_acc[n][r] += cf * acc[r];
            }
        }
        cur ^= 1;
    }

    // n-major partial store: per n, each wave writes 512 contiguous bytes
    // (4 full 128B lines) -> no partial-line RMW.
    u16* sp = s_part + blk * (B_ * F_);
    const float sc = (MODE == 0) ? 0.1f : 1.f;
#pragma unroll
    for (int n = 0; n < NC_; ++n) {
        u16 h[4] __attribute__((aligned(8)));
#pragma unroll
        for (int r = 0; r < 4; ++r) h[r] = f2bf(s_acc[n][r] * sc);
        *(ushort4*)(sp + n * 2048 + b * 16 + q * 4) = *(const ushort4*)h;
    }
}

// Sum bf16 partials over NBLK groups (n-major layout, uint4 = 8 bf16 per
// load), squash along CLO=16. ADD: add vprev (v0+v1 for next pass's logits).
// Validated (R3 pass) with the n-major index remap.
template<int ADD>
__global__ void k_red(const u16* __restrict__ s_part,
                      const float* __restrict__ vprev, float* __restrict__ vout) {
    __shared__ float red[32 * 66];
    const int tid = threadIdx.x, blk = blockIdx.x;
    const int pid = tid & 7, part = tid >> 3;     // 8 uint4 lanes x 32 parts
    const uint4* sp4 = (const uint4*)s_part;      // 2560 uint4 per group
    const int base = blk * 8 + pid;               // uint4 column 0..2559
    float a[8];
#pragma unroll
    for (int j = 0; j < 8; ++j) a[j] = 0.f;
    for (int g = part; g < NBLK; g += 32) {       // 16 iterations
        uint4 uv = sp4[(size_t)g * 2560 + base];
        a[0] += bf2f((u16)(uv.x & 0xffff)); a[1] += bf2f((u16)(uv.x >> 16));
        a[2] += bf2f((u16)(uv.y & 0xffff)); a[3] += bf2f((u16)(uv.y >> 16));
        a[4] += bf2f((u16)(uv.z & 0xffff)); a[5] += bf2f((u16)(uv.z >> 16));
        a[6] += bf2f((u16)(uv.w & 0xffff)); a[7] += bf2f((u16)(uv.w >> 16));
    }
#pragma unroll
    for (int j = 0; j < 8; ++j) red[part * 66 + pid * 8 + j] = a[j];
    __syncthreads();
    if (tid < 32) {
        float s0 = 0.f, s1 = 0.f;
#pragma unroll
        for (int k = 0; k < 32; ++k) {
            s0 += red[k * 66 + tid * 2];
            s1 += red[k * 66 + tid * 2 + 1];
        }
        float sq = s0 * s0 + s1 * s1;
        sq += __shfl_xor(sq, 1);    // 8 lanes = 16 elems of one (b,n) row
        sq += __shfl_xor(sq, 2);
        sq += __shfl_xor(sq, 4);
        float fct = sq / ((1.f + sq) * sqrtf(sq));
        // remap n-major partial column -> b-major output offset
        const int i = blk * 8 + (tid >> 2);        // uint4 column of this pair
        const int n = i >> 8, bb = (i & 255) >> 1, hh = i & 1;
        const int f0 = bb * 160 + n * 16 + hh * 8 + 2 * (tid & 3);
        float2 o = make_float2(s0 * fct, s1 * fct);
        if (ADD) {
            float2 pv = *(const float2*)(vprev + f0);
            o.x += pv.x; o.y += pv.y;
        }
        *(float2*)(vout + f0) = o;
    }
}

extern "C" void kernel_launch(void* const* d_in, const int* in_sizes, int n_in,
                              void* d_out, int out_size, void* d_ws, size_t ws_size,
                              hipStream_t stream) {
    const float* tensor = (const float*)d_in[0];
    const float* weight = (const float*)d_in[1];
    float* out = (float*)d_out;
    char* ws = (char*)d_ws;

    u16*   xb     = (u16*)(ws);                       // 16,777,216 B
    u16*   wb     = (u16*)(ws + 16777216);            // 20,971,520 B
    u16*   s_part = (u16*)(ws + 37748736);            // 512*40960 B = 20,971,520 B
    float* v0     = (float*)(ws + 58720256);          // 81,920 B
    float* vs     = (float*)(ws + 58802176);          // 81,920 B (v0 + v1)

    k_prep<<<6144, 256, 0, stream>>>(tensor, weight, xb, wb);

    k_pass<0><<<NBLK, NTHR, 0, stream>>>(xb, wb, nullptr, s_part);
    k_red<0><<<320, 256, 0, stream>>>(s_part, nullptr, v0);
    k_pass<1><<<NBLK, NTHR, 0, stream>>>(xb, wb, v0, s_part);
    k_red<1><<<320, 256, 0, stream>>>(s_part, v0, vs);
    k_pass<2><<<NBLK, NTHR, 0, stream>>>(xb, wb, vs, s_part);
    k_red<0><<<320, 256, 0, stream>>>(s_part, nullptr, out);
}